// Round 10
// baseline (438.377 us; speedup 1.0000x reference)
//
#include <hip/hip_runtime.h>
#include <math.h>

constexpr int B = 2, C = 16, H = 128, W = 128;
constexpr int HW = H * W;

// xpad: [B,16,146,148]; orig (h,w) -> (h+9, w+9); pads zeroed by conv1
constexpr int XR = 146, XS = 148, XCH = XR * XS;
constexpr size_t XPAD_ELEMS = (size_t)B * C * XCH;

// ypad: [B,16,130,136]; orig (h,w) -> (h+1, w+4); pads zeroed by kpn19
constexpr int YR = 130, YS = 136, YCH = YR * YS;

__device__ __forceinline__ float4 ld4(const float* p) { return *(const float4*)p; }

// ===========================================================================
// kpn19: per-pixel 19x19 conv, async global_load_lds ring pipeline (T3+T4).
// Block = 256 thr = 16 px-quads (64 px) x 16 ch. Grid = wb2 x h128 x b2 = 512.
// Slot (10240 B): [0,1216) kern[kw 0..18][px 0..63]
//                 [1216,2560) x[c 0..15][col 0..83]  (cols w0..w0+83)
// Ring of 6 slots = 60 KB -> 2 blocks/CU. Stage = 640 float4 = 160/wave =
// 3 global_load_lds per wave (3rd predicated lane<32 -> UNIFORM instr count
// across all 4 waves, so counted vmcnt is sound). Steady vmcnt(12) keeps 4
// steps in flight (5-step lookahead). Never drains to 0 mid-loop.
// Compute: pure LDS reads (2-way/uniform-floor banks) + 76 FMA. 1 barrier/step.
// ===========================================================================
constexpr int NSLOT = 6, SLOTF = 2560, XOFF = 1216;

__global__ __launch_bounds__(256) void kpn19(
    const float* __restrict__ xpad,  // [B,16,146,148]
    const float* __restrict__ kern,  // [B,361,128,128]
    float* __restrict__ ypad)        // [B,16,130,136]
{
    __shared__ __align__(16) float slots[NSLOT][SLOTF];   // 61,440 B

    int tid = threadIdx.x;
    int lane = tid & 63, wid = tid >> 6;
    int pq = tid & 15, c = tid >> 4;
    int blk = blockIdx.x;            // 512 = wb2 x h128 x b2
    int wb = blk & 1;
    int h  = (blk >> 1) & 127;
    int b  = blk >> 8;
    int w0 = wb * 64;

    // ---- ypad pad zeroing (replaces memset) ----
    if (tid < 64) {
        int pl = tid >> 2, i = tid & 3;
        int col = wb ? 132 + i : i;
        ypad[((size_t)(b * C + pl) * YR + (h + 1)) * YS + col] = 0.f;
    }
    if (h == 0 || h == 127) {
        int r = (h == 0) ? 0 : 129;
        for (int f = tid; f < 1088; f += 256) {
            int pl = f / 68, col = wb * 68 + f % 68;
            ypad[((size_t)(b * C + pl) * YR + r) * YS + col] = 0.f;
        }
    }

    // ---- per-lane staging sources (chunk m -> src ptr + per-step stride) ----
    // m in [0,304): kern, kw=m>>4, q=m&15; m in [304,640): x, c'=g/21, col4=g%21
    const float *src0, *src1, *src2;
    int str0, str1, str2;
    auto mapsrc = [&](int m, const float*& p, int& st) {
        if (m < 304) {
            p = kern + ((size_t)(b * 361 + (m >> 4)) * H + h) * W + w0 + (m & 15) * 4;
            st = 19 * HW;
        } else {
            int g = m - 304;
            int q = g % 21;
            int cc = g / 21; if (cc > 15) cc = 15;   // masked lanes: keep in-bounds
            p = xpad + (size_t)(b * C + cc) * XCH + (size_t)h * XS + w0 + q * 4;
            st = XS;
        }
    };
    mapsrc(wid * 160 + lane,        src0, str0);
    mapsrc(wid * 160 + 64 + lane,   src1, str1);
    mapsrc(wid * 160 + 128 + lane,  src2, str2);

    auto STAGE = [&](int s) {
        __builtin_amdgcn_global_load_lds((const void*)src0,
            (void*)&slots[s][(wid * 160 + 0) * 4], 16, 0, 0);
        __builtin_amdgcn_global_load_lds((const void*)src1,
            (void*)&slots[s][(wid * 160 + 64) * 4], 16, 0, 0);
        if (lane < 32)
            __builtin_amdgcn_global_load_lds((const void*)src2,
                (void*)&slots[s][(wid * 160 + 128) * 4], 16, 0, 0);
        src0 += str0; src1 += str1; src2 += str2;
    };

    float4 acc = make_float4(0.f, 0.f, 0.f, 0.f);

    auto COMP = [&](int s) {
        const float* xs = &slots[s][XOFF + c * 84 + pq * 4];
        float4 x0 = ld4(xs),      x1 = ld4(xs + 4),  x2 = ld4(xs + 8),
               x3 = ld4(xs + 12), x4 = ld4(xs + 16), x5 = ld4(xs + 20);
        float xv[24] = {x0.x,x0.y,x0.z,x0.w, x1.x,x1.y,x1.z,x1.w,
                        x2.x,x2.y,x2.z,x2.w, x3.x,x3.y,x3.z,x3.w,
                        x4.x,x4.y,x4.z,x4.w, x5.x,x5.y,x5.z,x5.w};
        const float* ks = &slots[s][pq * 4];
        #pragma unroll
        for (int kw = 0; kw < 19; ++kw) {
            float4 k = ld4(ks + kw * 64);
            acc.x = fmaf(xv[kw + 0], k.x, acc.x);
            acc.y = fmaf(xv[kw + 1], k.y, acc.y);
            acc.z = fmaf(xv[kw + 2], k.z, acc.z);
            acc.w = fmaf(xv[kw + 3], k.w, acc.w);
        }
    };

    // Prologue: stage steps 0..4 -> 15 loads/wave outstanding.
    STAGE(0); STAGE(1); STAGE(2); STAGE(3); STAGE(4);

#define KSTEP(k, NW)                                                          \
    asm volatile("s_waitcnt vmcnt(" #NW ")" ::: "memory");                    \
    __builtin_amdgcn_sched_barrier(0);                                        \
    __builtin_amdgcn_s_barrier();                                             \
    __builtin_amdgcn_sched_barrier(0);                                        \
    if ((k) + 5 < 19) { STAGE(((k) + 5) % NSLOT); }                           \
    __builtin_amdgcn_sched_barrier(0);                                        \
    COMP((k) % NSLOT);                                                        \
    __builtin_amdgcn_sched_barrier(0);

    KSTEP(0, 12)  KSTEP(1, 12)  KSTEP(2, 12)  KSTEP(3, 12)  KSTEP(4, 12)
    KSTEP(5, 12)  KSTEP(6, 12)  KSTEP(7, 12)  KSTEP(8, 12)  KSTEP(9, 12)
    KSTEP(10, 12) KSTEP(11, 12) KSTEP(12, 12) KSTEP(13, 12) KSTEP(14, 12)
    KSTEP(15, 9)  KSTEP(16, 6)  KSTEP(17, 3)  KSTEP(18, 0)
#undef KSTEP

    float* yp = ypad + ((size_t)(b * C + c) * YR + (h + 1)) * YS + (w0 + pq * 4 + 4);
    *(float4*)yp = acc;
}

// ===========================================================================
// conv1: 3x3 conv (pad 1) + exact GELU -> xpad. Rows staged in LDS (one-shot),
// taps become conflict-free ds_read_b32. Thread = 1 px x 4 oc.
// Block = 128 px x 2 ocg; grid = half2 x h128 x b2 = 512.
// ===========================================================================
__global__ __launch_bounds__(256) void conv1_gelu(
    const float* __restrict__ in, const float* __restrict__ w1,
    const float* __restrict__ b1, float* __restrict__ xpad)
{
    __shared__ float ws[2304];
    __shared__ float bs[16];
    __shared__ __align__(16) float xs[16][3][128];   // 24 KB

    int tid = threadIdx.x;
    for (int i = tid; i < 2304; i += 256) ws[i] = w1[i];
    if (tid < 16) bs[tid] = b1[tid];

    int px  = tid & 127;
    int ocg = tid >> 7;                  // wave-uniform
    int blk = blockIdx.x;                // 512 = half2 x h128 x b2
    int half = blk & 1;
    int h   = (blk >> 1) & 127;
    int b   = blk >> 8;
    int oc0 = half * 8 + ocg * 4;

    // ---- xpad pad zeroing for the 8 planes this block owns ----
    if (tid < 160) {
        int j = tid / 20, i = tid % 20;
        int col = (i < 9) ? i : 128 + i;             // 0..8, 137..147
        xpad[((size_t)(b * C + half * 8 + j) * XR + (h + 9)) * XS + col] = 0.f;
    }
    if (h == 0 || h == 127) {
        int r0 = (h == 0) ? 0 : 137;
        for (int f = tid; f < 8 * 9 * XS; f += 256) {
            int j = f / (9 * XS), rem = f % (9 * XS);
            int r = r0 + rem / XS, col = rem % XS;
            xpad[((size_t)(b * C + half * 8 + j) * XR + r) * XS + col] = 0.f;
        }
    }

    // ---- stage rows h-1..h+1 x 16 ic into LDS (coalesced float4) ----
    const float4 z4 = make_float4(0.f, 0.f, 0.f, 0.f);
    #pragma unroll
    for (int j = 0; j < 6; ++j) {
        int m = tid + j * 256;           // < 1536
        int ic = m / 96, rem = m - ic * 96, r = rem >> 5, q = rem & 31;
        int row = h + r - 1;
        float4 v = ((unsigned)row < 128u)
                 ? ld4(in + ((size_t)(b * C + ic) * H + row) * W + q * 4) : z4;
        *(float4*)&xs[ic][r][q * 4] = v;
    }
    __syncthreads();

    bool wm = (px > 0), wp = (px < 127);
    float a0 = 0.f, a1 = 0.f, a2 = 0.f, a3 = 0.f;

    #pragma unroll
    for (int ic = 0; ic < 16; ++ic) {
        float t[9];
        #pragma unroll
        for (int r = 0; r < 3; ++r) {
            t[r * 3 + 0] = wm ? xs[ic][r][px - 1] : 0.f;
            t[r * 3 + 1] = xs[ic][r][px];
            t[r * 3 + 2] = wp ? xs[ic][r][px + 1] : 0.f;
        }
        #pragma unroll
        for (int j = 0; j < 4; ++j) {
            const float* wp9 = ws + (oc0 + j) * 144 + ic * 9;
            float s = fmaf(wp9[0], t[0], fmaf(wp9[1], t[1], fmaf(wp9[2], t[2],
                      fmaf(wp9[3], t[3], fmaf(wp9[4], t[4], fmaf(wp9[5], t[5],
                      fmaf(wp9[6], t[6], fmaf(wp9[7], t[7], wp9[8] * t[8]))))))));
            if (j == 0) a0 += s; else if (j == 1) a1 += s;
            else if (j == 2) a2 += s; else a3 += s;
        }
    }

    float* xp = xpad + ((size_t)(b * C + oc0) * XR + (h + 9)) * XS + (px + 9);
    float v;
    v = a0 + bs[oc0 + 0]; xp[0]       = 0.5f * v * (1.0f + erff(v * 0.70710678f));
    v = a1 + bs[oc0 + 1]; xp[XCH]     = 0.5f * v * (1.0f + erff(v * 0.70710678f));
    v = a2 + bs[oc0 + 2]; xp[2 * XCH] = 0.5f * v * (1.0f + erff(v * 0.70710678f));
    v = a3 + bs[oc0 + 3]; xp[3 * XCH] = 0.5f * v * (1.0f + erff(v * 0.70710678f));
}

// ===========================================================================
// conv2: 3x3 conv (pad 1) + sigmoid -> out. Padded-y rows staged in LDS;
// unconditional taps. Same geometry as conv1.
// ===========================================================================
__global__ __launch_bounds__(256) void conv2_sig(
    const float* __restrict__ ypad, const float* __restrict__ w2,
    const float* __restrict__ b2, float* __restrict__ out)
{
    __shared__ float ws[2304];
    __shared__ float bs[16];
    __shared__ __align__(16) float ys[16][3][136];   // 26.1 KB

    int tid = threadIdx.x;
    for (int i = tid; i < 2304; i += 256) ws[i] = w2[i];
    if (tid < 16) bs[tid] = b2[tid];

    int px  = tid & 127;
    int ocg = tid >> 7;
    int blk = blockIdx.x;                // 512 = half2 x h128 x b2
    int half = blk & 1;
    int h   = (blk >> 1) & 127;
    int b   = blk >> 8;
    int oc0 = half * 8 + ocg * 4;

    // stage padded rows h..h+2 x 16 ic, cols 0..135
    #pragma unroll
    for (int j = 0; j < 7; ++j) {
        int m = tid + j * 256;
        if (m < 1632) {
            int ic = m / 102, rem = m - ic * 102, r = rem / 34, q = rem % 34;
            float4 v = ld4(ypad + ((size_t)(b * C + ic) * YR + (h + r)) * YS + q * 4);
            *(float4*)&ys[ic][r][q * 4] = v;
        }
    }
    __syncthreads();

    float a0 = 0.f, a1 = 0.f, a2 = 0.f, a3 = 0.f;

    #pragma unroll
    for (int ic = 0; ic < 16; ++ic) {
        float t[9];
        #pragma unroll
        for (int r = 0; r < 3; ++r) {
            t[r * 3 + 0] = ys[ic][r][px + 3];
            t[r * 3 + 1] = ys[ic][r][px + 4];
            t[r * 3 + 2] = ys[ic][r][px + 5];
        }
        #pragma unroll
        for (int j = 0; j < 4; ++j) {
            const float* wp9 = ws + (oc0 + j) * 144 + ic * 9;
            float s = fmaf(wp9[0], t[0], fmaf(wp9[1], t[1], fmaf(wp9[2], t[2],
                      fmaf(wp9[3], t[3], fmaf(wp9[4], t[4], fmaf(wp9[5], t[5],
                      fmaf(wp9[6], t[6], fmaf(wp9[7], t[7], wp9[8] * t[8]))))))));
            if (j == 0) a0 += s; else if (j == 1) a1 += s;
            else if (j == 2) a2 += s; else a3 += s;
        }
    }

    float* op = out + ((size_t)(b * C + oc0) * H + h) * W + px;
    float v;
    v = a0 + bs[oc0 + 0]; op[0]      = 1.0f / (1.0f + expf(-v));
    v = a1 + bs[oc0 + 1]; op[HW]     = 1.0f / (1.0f + expf(-v));
    v = a2 + bs[oc0 + 2]; op[2 * HW] = 1.0f / (1.0f + expf(-v));
    v = a3 + bs[oc0 + 3]; op[3 * HW] = 1.0f / (1.0f + expf(-v));
}

// ---------------------------------------------------------------------------
extern "C" void kernel_launch(void* const* d_in, const int* in_sizes, int n_in,
                              void* d_out, int out_size, void* d_ws, size_t ws_size,
                              hipStream_t stream)
{
    const float* input  = (const float*)d_in[0];
    const float* kernel = (const float*)d_in[1];
    const float* w1     = (const float*)d_in[2];
    const float* b1     = (const float*)d_in[3];
    const float* w2     = (const float*)d_in[4];
    const float* b2     = (const float*)d_in[5];
    float* out = (float*)d_out;

    float* xpad = (float*)d_ws;
    float* ypad = xpad + XPAD_ELEMS;

    conv1_gelu<<<512, 256, 0, stream>>>(input, w1, b1, xpad);
    kpn19<<<512, 256, 0, stream>>>(xpad, kernel, ypad);
    conv2_sig<<<512, 256, 0, stream>>>(ypad, w2, b2, out);
}

// Round 12
// 73.886 us; speedup vs baseline: 5.9331x; 5.9331x over previous
//
#include <hip/hip_runtime.h>
#include <math.h>

constexpr int B = 2, C = 16, H = 128, W = 128;
constexpr int HW = H * W;

// xpad: [B,16,146,148]; orig (h,w) -> (h+9, w+9); pads zeroed by conv1
constexpr int XR = 146, XS = 148, XCH = XR * XS;
constexpr size_t XPAD_ELEMS = (size_t)B * C * XCH;

// ypad: [B,16,130,136]; orig (h,w) -> (h+1, w+4); pads zeroed by kpn19
constexpr int YR = 130, YS = 136, YCH = YR * YS;

// ===========================================================================
// kpn19: per-pixel 19x19 conv. Low-pressure batched-load structure:
// wave = 64 px lanes (256B coalesced kern loads), 4 waves = 4 ch-groups that
// read IDENTICAL kern addresses (L1 broadcast). Per kh: 19 independent scalar
// kern loads (kv[19], ~19 VGPR) -> fence -> 76 x-loads + 76 FMAs. The fence
// placement lets batch kh+1 interleave with compute kh (1-deep pipeline),
// while total VGPR stays ~60 so the allocator has no sink/spill incentive.
// Block 256 = 64 px x 4 cg (cg owns ch 4cg..4cg+3). Grid = wb2 x h128 x b2
// = 512 blocks (2/CU, 8 waves/CU).
// ===========================================================================
__global__ __launch_bounds__(256) void kpn19(
    const float* __restrict__ xpad,  // [B,16,146,148]
    const float* __restrict__ kern,  // [B,361,128,128]
    float* __restrict__ ypad)        // [B,16,130,136]
{
    int tid  = threadIdx.x;
    int lane = tid & 63;
    int cg   = tid >> 6;             // wave-uniform, 0..3
    int blk  = blockIdx.x;           // 512 = wb2 x h128 x b2
    int wb   = blk & 1;
    int h    = (blk >> 1) & 127;
    int b    = blk >> 8;
    int px   = wb * 64 + lane;
    int c0   = cg * 4;

    // ---- ypad pad zeroing (replaces memset; proven in r9/r10) ----
    if (tid < 64) {
        int pl = tid >> 2, i = tid & 3;
        int col = wb ? 132 + i : i;
        ypad[((size_t)(b * C + pl) * YR + (h + 1)) * YS + col] = 0.f;
    }
    if (h == 0 || h == 127) {
        int r = (h == 0) ? 0 : 129;
        for (int f = tid; f < 1088; f += 256) {
            int pl = f / 68, col = wb * 68 + f % 68;
            ypad[((size_t)(b * C + pl) * YR + r) * YS + col] = 0.f;
        }
    }

    const float* kp = kern + (size_t)b * 361 * HW + (size_t)h * W + px;
    const float* x0 = xpad + (size_t)(b * C + c0) * XCH + (size_t)h * XS + px;

    float a0 = 0.f, a1 = 0.f, a2 = 0.f, a3 = 0.f;

    for (int kh = 0; kh < 19; ++kh) {
        // --- batch: 19 independent coalesced kern loads (one kh row) ---
        float kv[19];
        const float* kpr = kp + (size_t)(kh * 19) * HW;
        #pragma unroll
        for (int kw = 0; kw < 19; ++kw)
            kv[kw] = kpr[(size_t)kw * HW];
        __builtin_amdgcn_sched_barrier(0);   // batch stays ahead of compute;
                                             // next iter's batch may overlap
        // --- compute: x taps (L1/L2-resident) x kern row ---
        const float* xr = x0 + (size_t)kh * XS;
        #pragma unroll
        for (int kw = 0; kw < 19; ++kw) {
            float k = kv[kw];
            a0 = fmaf(xr[kw],            k, a0);
            a1 = fmaf(xr[kw + XCH],      k, a1);
            a2 = fmaf(xr[kw + 2 * XCH],  k, a2);
            a3 = fmaf(xr[kw + 3 * XCH],  k, a3);
        }
    }

    float* yp = ypad + ((size_t)(b * C + c0) * YR + (h + 1)) * YS + (px + 4);
    yp[0]           = a0;
    yp[YCH]         = a1;
    yp[2 * YCH]     = a2;
    yp[3 * YCH]     = a3;
}

// ===========================================================================
// conv1: 3x3 conv (pad 1) + exact GELU -> xpad (round-9 proven version).
// Thread = 1 px x 2 oc; grid = ocq4 x h128 x b2 = 1024. Zeroes xpad pads.
// ===========================================================================
__global__ __launch_bounds__(256) void conv1_gelu(
    const float* __restrict__ in, const float* __restrict__ w1,
    const float* __restrict__ b1, float* __restrict__ xpad)
{
    __shared__ float ws[2304];
    __shared__ float bs[16];
    for (int i = threadIdx.x; i < 2304; i += 256) ws[i] = w1[i];
    if (threadIdx.x < 16) bs[threadIdx.x] = b1[threadIdx.x];
    __syncthreads();

    int px  = threadIdx.x & 127;
    int opg = threadIdx.x >> 7;          // wave-uniform
    int blk = blockIdx.x;                // 1024 = ocq4 x h128 x b2
    int ocq = blk & 3;
    int h   = (blk >> 2) & 127;
    int b   = blk >> 9;
    int oc0 = ocq * 4 + opg * 2;

    // xpad pad zeroing: col pads of row h+9 for this block's 4 planes
    if (threadIdx.x < 80) {
        int j = threadIdx.x / 20, i = threadIdx.x % 20;
        int col = (i < 9) ? i : 128 + i;             // 0..8, 137..147
        xpad[((size_t)(b * C + ocq * 4 + j) * XR + (h + 9)) * XS + col] = 0.f;
    }
    if (h == 0 || h == 127) {
        int r0 = (h == 0) ? 0 : 137;
        for (int f = threadIdx.x; f < 4 * 9 * XS; f += 256) {
            int j = f / (9 * XS), rem = f % (9 * XS);
            int r = r0 + rem / XS, col = rem % XS;
            xpad[((size_t)(b * C + ocq * 4 + j) * XR + r) * XS + col] = 0.f;
        }
    }

    const float* inb = in + (size_t)b * C * HW;
    bool hm = (h > 0), hp = (h < 127), wm = (px > 0), wp = (px < 127);

    float a0 = 0.f, a1 = 0.f;
    #pragma unroll
    for (int ic = 0; ic < 16; ++ic) {
        const float* p0 = inb + (size_t)ic * HW + (size_t)h * W + px;
        float t0 = (hm && wm) ? p0[-W - 1] : 0.f;
        float t1 = hm         ? p0[-W]     : 0.f;
        float t2 = (hm && wp) ? p0[-W + 1] : 0.f;
        float t3 = wm         ? p0[-1]     : 0.f;
        float t4 =              p0[0];
        float t5 = wp         ? p0[1]      : 0.f;
        float t6 = (hp && wm) ? p0[W - 1]  : 0.f;
        float t7 = hp         ? p0[W]      : 0.f;
        float t8 = (hp && wp) ? p0[W + 1]  : 0.f;
        #pragma unroll
        for (int j = 0; j < 2; ++j) {
            const float* wp9 = ws + (oc0 + j) * 144 + ic * 9;
            float s = fmaf(wp9[0], t0, fmaf(wp9[1], t1, fmaf(wp9[2], t2,
                      fmaf(wp9[3], t3, fmaf(wp9[4], t4, fmaf(wp9[5], t5,
                      fmaf(wp9[6], t6, fmaf(wp9[7], t7, wp9[8] * t8))))))));
            if (j == 0) a0 += s; else a1 += s;
        }
    }

    float* xp = xpad + ((size_t)(b * C + oc0) * XR + (h + 9)) * XS + (px + 9);
    float v;
    v = a0 + bs[oc0 + 0]; xp[0]   = 0.5f * v * (1.0f + erff(v * 0.70710678f));
    v = a1 + bs[oc0 + 1]; xp[XCH] = 0.5f * v * (1.0f + erff(v * 0.70710678f));
}

// ===========================================================================
// conv2: 3x3 conv (pad 1) + sigmoid -> out (round-9 proven version).
// ===========================================================================
__global__ __launch_bounds__(256) void conv2_sig(
    const float* __restrict__ ypad, const float* __restrict__ w2,
    const float* __restrict__ b2, float* __restrict__ out)
{
    __shared__ float ws[2304];
    __shared__ float bs[16];
    for (int i = threadIdx.x; i < 2304; i += 256) ws[i] = w2[i];
    if (threadIdx.x < 16) bs[threadIdx.x] = b2[threadIdx.x];
    __syncthreads();

    int px  = threadIdx.x & 127;
    int opg = threadIdx.x >> 7;
    int blk = blockIdx.x;                // 1024 = ocq4 x h128 x b2
    int ocq = blk & 3;
    int h   = (blk >> 2) & 127;
    int b   = blk >> 9;
    int oc0 = ocq * 4 + opg * 2;

    float a0 = 0.f, a1 = 0.f;
    #pragma unroll
    for (int ic = 0; ic < 16; ++ic) {
        const float* p0 = ypad + ((size_t)(b * C + ic) * YR + (h + 1)) * YS + (px + 4);
        float t0 = p0[-YS - 1], t1 = p0[-YS], t2 = p0[-YS + 1];
        float t3 = p0[-1],      t4 = p0[0],   t5 = p0[1];
        float t6 = p0[YS - 1],  t7 = p0[YS],  t8 = p0[YS + 1];
        #pragma unroll
        for (int j = 0; j < 2; ++j) {
            const float* wp9 = ws + (oc0 + j) * 144 + ic * 9;
            float s = fmaf(wp9[0], t0, fmaf(wp9[1], t1, fmaf(wp9[2], t2,
                      fmaf(wp9[3], t3, fmaf(wp9[4], t4, fmaf(wp9[5], t5,
                      fmaf(wp9[6], t6, fmaf(wp9[7], t7, wp9[8] * t8))))))));
            if (j == 0) a0 += s; else a1 += s;
        }
    }

    float* op = out + ((size_t)(b * C + oc0) * H + h) * W + px;
    float v;
    v = a0 + bs[oc0 + 0]; op[0]  = 1.0f / (1.0f + expf(-v));
    v = a1 + bs[oc0 + 1]; op[HW] = 1.0f / (1.0f + expf(-v));
}

// ---------------------------------------------------------------------------
extern "C" void kernel_launch(void* const* d_in, const int* in_sizes, int n_in,
                              void* d_out, int out_size, void* d_ws, size_t ws_size,
                              hipStream_t stream)
{
    const float* input  = (const float*)d_in[0];
    const float* kernel = (const float*)d_in[1];
    const float* w1     = (const float*)d_in[2];
    const float* b1     = (const float*)d_in[3];
    const float* w2     = (const float*)d_in[4];
    const float* b2     = (const float*)d_in[5];
    float* out = (float*)d_out;

    float* xpad = (float*)d_ws;
    float* ypad = xpad + XPAD_ELEMS;

    conv1_gelu<<<1024, 256, 0, stream>>>(input, w1, b1, xpad);
    kpn19<<<512, 256, 0, stream>>>(xpad, kernel, ypad);
    conv2_sig<<<1024, 256, 0, stream>>>(ypad, w2, b2, out);
}